// Round 13
// baseline (183.434 us; speedup 1.0000x reference)
//
#include <hip/hip_runtime.h>
#include <hip/hip_bf16.h>

// FiLM + 2-layer preact resnet. N=65536, H=256, C=512.
// Round 13: K1 reshaped to the K2 template. One block per 64 rows computes
// FULL gb (no cond duplicate): full-K cond bf16 in 64KB LDS, gamma/beta
// time-split flat 32-step MFMA loop (acc 64 regs), x staged post-GEMM1 in
// 4 small chunks, r1 -> ws. All f32->bf16 via v_cvt_pk (hw RNE), killing
// the 5-op/elem manual conversion that made VALUBusy > MfmaUtil.
// K2 unchanged from round 12 (GEMM2+3 + residual, ~17us, L3-resident).

typedef __attribute__((ext_vector_type(8))) short bf16x8;   // 8 bf16 = 4 VGPR
typedef __attribute__((ext_vector_type(4))) float f32x4;    // MFMA C/D

typedef unsigned short ushort_t;
typedef unsigned int uint_t;

__device__ __forceinline__ ushort_t f2bfh(float f) {
  __hip_bfloat16 h = __float2bfloat16(f);            // RNE, hw cvt
  return *reinterpret_cast<ushort_t*>(&h);
}
__device__ __forceinline__ float bf2f(ushort_t s) {
  union { uint_t u; float f; } v; v.u = ((uint_t)s) << 16;
  return v.f;
}
__device__ __forceinline__ bf16x8 ldfrag(const ushort_t* p) {
  return *reinterpret_cast<const bf16x8*>(p);
}
__device__ __forceinline__ bf16x8 pack8(float4 a, float4 b) {
  union { bf16x8 v; __hip_bfloat162 h[4]; } u;       // v_cvt_pk_bf16_f32 x4
  u.h[0] = __float22bfloat162_rn(float2{a.x, a.y});
  u.h[1] = __float22bfloat162_rn(float2{a.z, a.w});
  u.h[2] = __float22bfloat162_rn(float2{b.x, b.y});
  u.h[3] = __float22bfloat162_rn(float2{b.z, b.w});
  return u.v;
}

// ---------------------------------------------------------------------------
// Pack weights (fp32 row-major [K][Ncols]) into bf16 MFMA-B fragment order:
//   p[((nt*KT + kt)*64 + lane)*8 + j] = W[kt*32 + (lane>>4)*8 + j][nt*16 + (lane&15)]
// ---------------------------------------------------------------------------
__global__ void pack_weights(const float* __restrict__ Wf,
                             const float* __restrict__ W1,
                             const float* __restrict__ W2,
                             ushort_t* __restrict__ p1,
                             ushort_t* __restrict__ pW1,
                             ushort_t* __restrict__ pW2) {
  int u = blockIdx.x * 256 + threadIdx.x;
  if (u < 32768) {
    int lane = u & 63, rest = u >> 6;
    int kt = rest & 15;
    int kb = kt * 32 + (lane >> 4) * 8;
    int col = (rest >> 4) * 16 + (lane & 15);
#pragma unroll
    for (int j = 0; j < 8; ++j)
      p1[(size_t)u * 8 + j] = f2bfh(Wf[(size_t)(kb + j) * 512 + col]);
  } else if (u < 40960) {
    int v = u - 32768;
    int lane = v & 63;
    int kt = (v >> 6) & 7;
    int kb = kt * 32 + (lane >> 4) * 8;
    int col = (v >> 9) * 16 + (lane & 15);
#pragma unroll
    for (int j = 0; j < 8; ++j)
      pW1[(size_t)v * 8 + j] = f2bfh(W1[(size_t)(kb + j) * 256 + col]);
  } else if (u < 49152) {
    int v = u - 40960;
    int lane = v & 63;
    int kt = (v >> 6) & 7;
    int kb = kt * 32 + (lane >> 4) * 8;
    int col = (v >> 9) * 16 + (lane & 15);
#pragma unroll
    for (int j = 0; j < 8; ++j)
      pW2[(size_t)v * 8 + j] = f2bfh(W2[(size_t)(kb + j) * 256 + col]);
  }
}

// ---------------------------------------------------------------------------
// K1: 1024 blocks x 64 rows, 8 waves (512 thr); wave w owns gb cols
// [w*32,+32) of gamma AND beta (panels ntg=w*2+tt, ntb=16+w*2+tt).
// LDS 64KB: phase 1 cond bf16 [64][512] swz; phase 2 B=[32K,64K) x bf16
// [64][256], A=[0,32K) r1 bf16 [64][256]. XOR swz byte ^= (row&15)<<4.
// GEMM1 = flat 32 steps (s<16 gamma acc_g, s>=16 beta acc_b), 2-slot B pipe.
// ---------------------------------------------------------------------------
__global__ __launch_bounds__(512, 2)
void k_gemm1_film(const float* __restrict__ x, const float* __restrict__ cond,
                  const float* __restrict__ b_film,
                  const ushort_t* __restrict__ p1,
                  ushort_t* __restrict__ r1g) {
  __shared__ __align__(16) char lds[65536];
  char* A = lds;
  char* B = lds + 32768;
  const int r0 = blockIdx.x * 64;
  const int t = threadIdx.x;
  const int w = t >> 6;
  const int l = t & 63;
  const int l15 = l & 15;
  const int lhi = l >> 4;

  float bgv[2], bbv[2];
#pragma unroll
  for (int tt = 0; tt < 2; ++tt) {
    int colg = w * 32 + tt * 16 + l15;
    bgv[tt] = b_film[colg];
    bbv[tt] = b_film[256 + colg];
  }

  // ---- stage cond full-K -> bf16 LDS [64][512] swz
#pragma unroll
  for (int it = 0; it < 8; ++it) {
    int u = it * 512 + t;
    int row = u >> 6, k8 = u & 63;
    const float4* cs = reinterpret_cast<const float4*>(cond + (size_t)(r0 + row) * 512 + k8 * 8);
    float4 a = cs[0], b = cs[1];
    int byte = row * 1024 + k8 * 16;
    byte ^= ((row & 15) << 4);
    *reinterpret_cast<bf16x8*>(lds + byte) = pack8(a, b);
  }
  // B-frag preload (s=0: gamma, kt=0)
  bf16x8 bb[2][2];
#pragma unroll
  for (int tt = 0; tt < 2; ++tt)
    bb[0][tt] = ldfrag(p1 + ((size_t)((w * 2 + tt) * 16 + 0) * 64 + l) * 8);
  __syncthreads();   // B1: cond staged

  // ---- GEMM1: 32 flat steps
  f32x4 acc_g[4][2], acc_b[4][2];
#pragma unroll
  for (int m = 0; m < 4; ++m)
#pragma unroll
    for (int n = 0; n < 2; ++n) {
      acc_g[m][n] = (f32x4){0.f, 0.f, 0.f, 0.f};
      acc_b[m][n] = (f32x4){0.f, 0.f, 0.f, 0.f};
    }

#pragma unroll
  for (int s = 0; s < 32; ++s) {
    const int cur = s & 1;
    if (s < 31) {
      const int sn = s + 1;
      const int ktn = sn & 15;
      const int base = (sn >> 4) ? 16 : 0;
#pragma unroll
      for (int tt = 0; tt < 2; ++tt) {
        int nt = base + w * 2 + tt;
        bb[cur ^ 1][tt] = ldfrag(p1 + ((size_t)(nt * 16 + ktn) * 64 + l) * 8);
      }
    }
    const int kt = s & 15;
    bf16x8 afr[4];
#pragma unroll
    for (int m = 0; m < 4; ++m) {
      int row = m * 16 + l15;
      int byte = row * 1024 + kt * 64 + lhi * 16;
      byte ^= ((row & 15) << 4);
      afr[m] = *reinterpret_cast<const bf16x8*>(lds + byte);
    }
    __builtin_amdgcn_s_setprio(1);
    if (s < 16) {
#pragma unroll
      for (int tt = 0; tt < 2; ++tt)
#pragma unroll
        for (int m = 0; m < 4; ++m)
          acc_g[m][tt] = __builtin_amdgcn_mfma_f32_16x16x32_bf16(afr[m], bb[cur][tt], acc_g[m][tt], 0, 0, 0);
    } else {
#pragma unroll
      for (int tt = 0; tt < 2; ++tt)
#pragma unroll
        for (int m = 0; m < 4; ++m)
          acc_b[m][tt] = __builtin_amdgcn_mfma_f32_16x16x32_bf16(afr[m], bb[cur][tt], acc_b[m][tt], 0, 0, 0);
    }
    __builtin_amdgcn_s_setprio(0);
  }
  __syncthreads();   // B2: all cond reads done -> LDS reusable

  // ---- x -> B [64][256] bf16 swz, 4 small chunks (8 regs live each)
#pragma unroll
  for (int c = 0; c < 4; ++c) {
    int u = c * 512 + t;
    int row = u >> 5, c8 = u & 31;
    const float4* xs = reinterpret_cast<const float4*>(x + (size_t)(r0 + row) * 256 + c8 * 8);
    float4 xa = xs[0], xb = xs[1];
    int byte = row * 512 + c8 * 16;
    byte ^= ((row & 15) << 4);
    *reinterpret_cast<bf16x8*>(B + byte) = pack8(xa, xb);
  }
  __syncthreads();   // B3: x staged

  // ---- FiLM: r1 = relu((acc_g+bg)*x + (acc_b+bb)) -> bf16 into A
#pragma unroll
  for (int m = 0; m < 4; ++m) {
#pragma unroll
    for (int tt = 0; tt < 2; ++tt) {
      int colg = w * 32 + tt * 16 + l15;
#pragma unroll
      for (int reg = 0; reg < 4; ++reg) {
        int row = m * 16 + lhi * 4 + reg;
        int byte = row * 512 + colg * 2;
        byte ^= ((row & 15) << 4);
        float xv = bf2f(*reinterpret_cast<const ushort_t*>(B + byte));
        float hv = fmaxf((acc_g[m][tt][reg] + bgv[tt]) * xv + (acc_b[m][tt][reg] + bbv[tt]), 0.f);
        *reinterpret_cast<ushort_t*>(A + byte) = f2bfh(hv);
      }
    }
  }
  __syncthreads();   // B4: r1 complete in A

  // ---- coalesced r1 writeout ([64 rows][32 units of 16B])
#pragma unroll
  for (int it = 0; it < 4; ++it) {
    int u = it * 512 + t;
    int row = u >> 5, c16 = u & 31;
    int byte = row * 512 + c16 * 16;
    byte ^= ((row & 15) << 4);
    bf16x8 v = *reinterpret_cast<const bf16x8*>(A + byte);
    *reinterpret_cast<bf16x8*>(r1g + (size_t)(r0 + row) * 256 + c16 * 8) = v;
  }
}

// ---------------------------------------------------------------------------
// K2: 1024 blocks x 64 rows, 8 waves; wave w owns out-cols [w*32,+32)
// (nt = w*2+tt). LDS 32KB region R: r1 bf16 [64][256] swz -> r2 in place ->
// epilogue fp32 [32][256] halves. XOR swizzle byte ^= (row&15)<<4.
// ---------------------------------------------------------------------------
__global__ __launch_bounds__(512, 2)
void k_mlp(const ushort_t* __restrict__ r1g, const float* __restrict__ x,
           const float* __restrict__ b1, const float* __restrict__ b2,
           const ushort_t* __restrict__ pW1, const ushort_t* __restrict__ pW2,
           float* __restrict__ out) {
  __shared__ __align__(16) char R[32768];
  const int r0 = blockIdx.x * 64;
  const int t = threadIdx.x;
  const int w = t >> 6;
  const int l = t & 63;
  const int l15 = l & 15;
  const int lhi = l >> 4;

  float b1v[2], b2v[2];
#pragma unroll
  for (int tt = 0; tt < 2; ++tt) {
    int col = w * 32 + tt * 16 + l15;
    b1v[tt] = b1[col];
    b2v[tt] = b2[col];
  }

  // ---- stage r1 tile (bf16, 16B/lane coalesced)
#pragma unroll
  for (int it = 0; it < 4; ++it) {
    int u = it * 512 + t;
    int row = u >> 5, c8 = u & 31;
    bf16x8 v = *reinterpret_cast<const bf16x8*>(r1g + (size_t)(r0 + row) * 256 + c8 * 8);
    int byte = row * 512 + c8 * 16;
    byte ^= ((row & 15) << 4);
    *reinterpret_cast<bf16x8*>(R + byte) = v;
  }
  bf16x8 bb2[2][2];
#pragma unroll
  for (int tt = 0; tt < 2; ++tt)
    bb2[0][tt] = ldfrag(pW1 + ((size_t)((w * 2 + tt) * 8 + 0) * 64 + l) * 8);
  __syncthreads();   // r1 staged

  // ---- GEMM2
  f32x4 acc2[4][2];
#pragma unroll
  for (int m = 0; m < 4; ++m)
#pragma unroll
    for (int n = 0; n < 2; ++n) acc2[m][n] = (f32x4){0.f, 0.f, 0.f, 0.f};

#pragma unroll
  for (int kt = 0; kt < 8; ++kt) {
    const int cur = kt & 1;
    if (kt < 7) {
#pragma unroll
      for (int tt = 0; tt < 2; ++tt)
        bb2[cur ^ 1][tt] = ldfrag(pW1 + ((size_t)((w * 2 + tt) * 8 + kt + 1) * 64 + l) * 8);
    }
    bf16x8 afr[4];
#pragma unroll
    for (int m = 0; m < 4; ++m) {
      int row = m * 16 + l15;
      int byte = row * 512 + kt * 64 + lhi * 16;
      byte ^= ((row & 15) << 4);
      afr[m] = *reinterpret_cast<const bf16x8*>(R + byte);
    }
    __builtin_amdgcn_s_setprio(1);
#pragma unroll
    for (int tt = 0; tt < 2; ++tt)
#pragma unroll
      for (int m = 0; m < 4; ++m)
        acc2[m][tt] = __builtin_amdgcn_mfma_f32_16x16x32_bf16(afr[m], bb2[cur][tt], acc2[m][tt], 0, 0, 0);
    __builtin_amdgcn_s_setprio(0);
  }
  __syncthreads();   // all r1 reads done -> in-place r2 safe

  // ---- r2 = relu(acc2+b1) in place; preload GEMM3 frags
  bf16x8 bb3[2][2];
#pragma unroll
  for (int tt = 0; tt < 2; ++tt)
    bb3[0][tt] = ldfrag(pW2 + ((size_t)((w * 2 + tt) * 8 + 0) * 64 + l) * 8);
#pragma unroll
  for (int tt = 0; tt < 2; ++tt) {
    int col = w * 32 + tt * 16 + l15;
#pragma unroll
    for (int m = 0; m < 4; ++m) {
#pragma unroll
      for (int reg = 0; reg < 4; ++reg) {
        int row = m * 16 + lhi * 4 + reg;
        int byte = row * 512 + col * 2;
        byte ^= ((row & 15) << 4);
        *reinterpret_cast<ushort_t*>(R + byte) = f2bfh(fmaxf(acc2[m][tt][reg] + b1v[tt], 0.f));
      }
    }
  }
  __syncthreads();   // r2 ready

  // ---- GEMM3
  f32x4 acc3[4][2];
#pragma unroll
  for (int m = 0; m < 4; ++m)
#pragma unroll
    for (int n = 0; n < 2; ++n) acc3[m][n] = (f32x4){0.f, 0.f, 0.f, 0.f};

#pragma unroll
  for (int kt = 0; kt < 8; ++kt) {
    const int cur = kt & 1;
    if (kt < 7) {
#pragma unroll
      for (int tt = 0; tt < 2; ++tt)
        bb3[cur ^ 1][tt] = ldfrag(pW2 + ((size_t)((w * 2 + tt) * 8 + kt + 1) * 64 + l) * 8);
    }
    bf16x8 afr[4];
#pragma unroll
    for (int m = 0; m < 4; ++m) {
      int row = m * 16 + l15;
      int byte = row * 512 + kt * 64 + lhi * 16;
      byte ^= ((row & 15) << 4);
      afr[m] = *reinterpret_cast<const bf16x8*>(R + byte);
    }
    __builtin_amdgcn_s_setprio(1);
#pragma unroll
    for (int tt = 0; tt < 2; ++tt)
#pragma unroll
      for (int m = 0; m < 4; ++m)
        acc3[m][tt] = __builtin_amdgcn_mfma_f32_16x16x32_bf16(afr[m], bb3[cur][tt], acc3[m][tt], 0, 0, 0);
    __builtin_amdgcn_s_setprio(0);
  }
  __syncthreads();   // all r2 reads done -> R free

  // ---- epilogue: two 32-row halves; +b2 at dump, +x at coalesced store
#pragma unroll
  for (int hh = 0; hh < 2; ++hh) {
    if (hh) __syncthreads();   // half-0 store reads done
#pragma unroll
    for (int tt = 0; tt < 2; ++tt) {
      int col = w * 32 + tt * 16 + l15;
#pragma unroll
      for (int mm = 0; mm < 2; ++mm) {
        int m = hh * 2 + mm;
#pragma unroll
        for (int reg = 0; reg < 4; ++reg) {
          int r = mm * 16 + lhi * 4 + reg;
          int byte = r * 1024 + col * 4;
          byte ^= ((r & 15) << 4);
          *reinterpret_cast<float*>(R + byte) = acc3[m][tt][reg] + b2v[tt];
        }
      }
    }
    __syncthreads();
#pragma unroll
    for (int i = 0; i < 4; ++i) {
      int u = i * 512 + t;
      int r = u >> 6, c4 = u & 63;   // [32 rows][64 units of 4 cols]
      int byte = r * 1024 + c4 * 16;
      byte ^= ((r & 15) << 4);
      f32x4 v = *reinterpret_cast<const f32x4*>(R + byte);
      int grow = hh * 32 + r;
      const float4 xres = *reinterpret_cast<const float4*>(
          x + (size_t)(r0 + grow) * 256 + c4 * 4);
      v.x += xres.x; v.y += xres.y; v.z += xres.z; v.w += xres.w;
      f32x4* op = reinterpret_cast<f32x4*>(out + (size_t)(r0 + grow) * 256 + c4 * 4);
      __builtin_nontemporal_store(v, op);
    }
  }
}

extern "C" void kernel_launch(void* const* d_in, const int* in_sizes, int n_in,
                              void* d_out, int out_size, void* d_ws, size_t ws_size,
                              hipStream_t stream) {
  const float* x      = (const float*)d_in[0];
  const float* cond   = (const float*)d_in[1];
  const float* W_film = (const float*)d_in[2];
  const float* b_film = (const float*)d_in[3];
  const float* W1     = (const float*)d_in[4];
  const float* b1     = (const float*)d_in[5];
  const float* W2     = (const float*)d_in[6];
  const float* b2     = (const float*)d_in[7];
  float* out = (float*)d_out;

  ushort_t* p1  = (ushort_t*)d_ws;       // 512KB
  ushort_t* pW1 = p1 + 262144;           // 128KB
  ushort_t* pW2 = pW1 + 65536;           // 128KB
  ushort_t* r1g = pW2 + 65536;           // 65536*256 bf16 = 32MB

  hipLaunchKernelGGL(pack_weights, dim3(192), dim3(256), 0, stream,
                     W_film, W1, W2, p1, pW1, pW2);
  hipLaunchKernelGGL(k_gemm1_film, dim3(1024), dim3(512), 0, stream,
                     x, cond, b_film, p1, r1g);
  hipLaunchKernelGGL(k_mlp, dim3(1024), dim3(512), 0, stream,
                     r1g, x, b1, b2, pW1, pW2, out);
}

// Round 14
// 111.242 us; speedup vs baseline: 1.6490x; 1.6490x over previous
//
#include <hip/hip_runtime.h>
#include <hip/hip_bf16.h>

// FiLM + 2-layer preact resnet. N=65536, H=256, C=512.
// Round 14: round-12 two-kernel split RESTORED (K1 column-split, acc 32/wave,
// 60 VGPR, no spill) with two surgical fixes:
//  (1) all f32->bf16 via v_cvt_pk_bf16_f32 (hw RNE) -- r12's manual 5-op
//      conversion made VALUBusy(17%) > MfmaUtil(15%);
//  (2) K1 __launch_bounds__(512,3): 60 VGPR fits the 84-box, 48KB LDS x3 =
//      144 <= 160KB -> 3 blocks/CU for more TLP.
// K2 unchanged from round 12 (~17us).

typedef __attribute__((ext_vector_type(8))) short bf16x8;   // 8 bf16 = 4 VGPR
typedef __attribute__((ext_vector_type(4))) float f32x4;    // MFMA C/D

typedef unsigned short ushort_t;
typedef unsigned int uint_t;

__device__ __forceinline__ ushort_t f2bfh(float f) {
  __hip_bfloat16 h = __float2bfloat16(f);            // RNE, hw cvt
  return *reinterpret_cast<ushort_t*>(&h);
}
__device__ __forceinline__ float bf2f(ushort_t s) {
  union { uint_t u; float f; } v; v.u = ((uint_t)s) << 16;
  return v.f;
}
__device__ __forceinline__ bf16x8 ldfrag(const ushort_t* p) {
  return *reinterpret_cast<const bf16x8*>(p);
}
__device__ __forceinline__ bf16x8 pack8(float4 a, float4 b) {
  union { bf16x8 v; __hip_bfloat162 h[4]; } u;       // v_cvt_pk_bf16_f32 x4
  u.h[0] = __float22bfloat162_rn(float2{a.x, a.y});
  u.h[1] = __float22bfloat162_rn(float2{a.z, a.w});
  u.h[2] = __float22bfloat162_rn(float2{b.x, b.y});
  u.h[3] = __float22bfloat162_rn(float2{b.z, b.w});
  return u.v;
}

// ---------------------------------------------------------------------------
// Pack weights (fp32 row-major [K][Ncols]) into bf16 MFMA-B fragment order:
//   p[((nt*KT + kt)*64 + lane)*8 + j] = W[kt*32 + (lane>>4)*8 + j][nt*16 + (lane&15)]
// ---------------------------------------------------------------------------
__global__ void pack_weights(const float* __restrict__ Wf,
                             const float* __restrict__ W1,
                             const float* __restrict__ W2,
                             ushort_t* __restrict__ p1,
                             ushort_t* __restrict__ pW1,
                             ushort_t* __restrict__ pW2) {
  int u = blockIdx.x * 256 + threadIdx.x;
  if (u < 32768) {
    int lane = u & 63, rest = u >> 6;
    int kt = rest & 15;
    int kb = kt * 32 + (lane >> 4) * 8;
    int col = (rest >> 4) * 16 + (lane & 15);
#pragma unroll
    for (int j = 0; j < 8; ++j)
      p1[(size_t)u * 8 + j] = f2bfh(Wf[(size_t)(kb + j) * 512 + col]);
  } else if (u < 40960) {
    int v = u - 32768;
    int lane = v & 63;
    int kt = (v >> 6) & 7;
    int kb = kt * 32 + (lane >> 4) * 8;
    int col = (v >> 9) * 16 + (lane & 15);
#pragma unroll
    for (int j = 0; j < 8; ++j)
      pW1[(size_t)v * 8 + j] = f2bfh(W1[(size_t)(kb + j) * 256 + col]);
  } else if (u < 49152) {
    int v = u - 40960;
    int lane = v & 63;
    int kt = (v >> 6) & 7;
    int kb = kt * 32 + (lane >> 4) * 8;
    int col = (v >> 9) * 16 + (lane & 15);
#pragma unroll
    for (int j = 0; j < 8; ++j)
      pW2[(size_t)v * 8 + j] = f2bfh(W2[(size_t)(kb + j) * 256 + col]);
  }
}

// ---------------------------------------------------------------------------
// K1: blockIdx -> (rb = bid>>1 : 64 rows, ch = bid&1 : r1-cols [ch*128,+128)).
// 8 waves; wave w owns 16 r1-cols -> gamma panel ntg=ch*8+w, beta ntb=16+ch*8+w.
// LDS 48KB: c0=[0,16K), c1=[16K,32K) cond chunk dbuf (bf16 [64][128] swz);
//           xb=[32K,48K) x-half bf16 [64][128] swz. trbuf reuses c0.
// XOR swizzle: byte ^= (row&15)<<4.
// ---------------------------------------------------------------------------
__global__ __launch_bounds__(512, 3)
void k_gemm1_film(const float* __restrict__ x, const float* __restrict__ cond,
                  const float* __restrict__ b_film,
                  const ushort_t* __restrict__ p1,
                  ushort_t* __restrict__ r1g) {
  __shared__ __align__(16) char lds[49152];
  char* c0 = lds;
  char* c1 = lds + 16384;
  char* xb = lds + 32768;
  const int rb = blockIdx.x >> 1;
  const int ch = blockIdx.x & 1;
  const int r0 = rb * 64;
  const int t = threadIdx.x;
  const int w = t >> 6;          // 0..7
  const int l = t & 63;
  const int l15 = l & 15;
  const int lhi = l >> 4;

  const float bgv = b_film[ch * 128 + w * 16 + l15];
  const float bbv = b_film[256 + ch * 128 + w * 16 + l15];
  const int ntg = ch * 8 + w;
  const int ntb = 16 + ch * 8 + w;

  // ---- stage cond chunk 0 + x-half
  {
    float4 cv[4], xv4[4];
#pragma unroll
    for (int p = 0; p < 2; ++p)
#pragma unroll
      for (int j = 0; j < 2; ++j) {
        int g = p * 1024 + t * 2 + j;         // float4 unit in [64][32]
        int row = g >> 5, c4 = g & 31;
        cv[p * 2 + j] = *reinterpret_cast<const float4*>(
            cond + (size_t)(r0 + row) * 512 + c4 * 4);
        xv4[p * 2 + j] = *reinterpret_cast<const float4*>(
            x + (size_t)(r0 + row) * 256 + ch * 128 + c4 * 4);
      }
#pragma unroll
    for (int p = 0; p < 2; ++p) {
      int g = p * 1024 + t * 2;
      int row = g >> 5, c4 = g & 31;
      int byte = row * 256 + c4 * 8;
      byte ^= ((row & 15) << 4);
      *reinterpret_cast<bf16x8*>(c0 + byte) = pack8(cv[p * 2], cv[p * 2 + 1]);
      *reinterpret_cast<bf16x8*>(xb + byte) = pack8(xv4[p * 2], xv4[p * 2 + 1]);
    }
  }
  // B-frag preload kt=0
  bf16x8 bb[2][2];
  bb[0][0] = ldfrag(p1 + ((size_t)(ntg * 16 + 0) * 64 + l) * 8);
  bb[0][1] = ldfrag(p1 + ((size_t)(ntb * 16 + 0) * 64 + l) * 8);
  __syncthreads();   // chunk 0 + x staged

  f32x4 accg[4], accb[4];
#pragma unroll
  for (int m = 0; m < 4; ++m) {
    accg[m] = (f32x4){0.f, 0.f, 0.f, 0.f};
    accb[m] = (f32x4){0.f, 0.f, 0.f, 0.f};
  }

#pragma unroll
  for (int q = 0; q < 4; ++q) {
    const char* rbuf = (q & 1) ? c1 : c0;
    // issue next-chunk loads early: latency hides under this chunk's MFMAs
    float4 cv[4];
    if (q < 3) {
#pragma unroll
      for (int p = 0; p < 2; ++p)
#pragma unroll
        for (int j = 0; j < 2; ++j) {
          int g = p * 1024 + t * 2 + j;
          int row = g >> 5, c4 = g & 31;
          cv[p * 2 + j] = *reinterpret_cast<const float4*>(
              cond + (size_t)(r0 + row) * 512 + (q + 1) * 128 + c4 * 4);
        }
    }
#pragma unroll
    for (int ktl = 0; ktl < 4; ++ktl) {
      const int kt = q * 4 + ktl;
      const int cur = kt & 1;
      if (kt < 15) {
        bb[cur ^ 1][0] = ldfrag(p1 + ((size_t)(ntg * 16 + kt + 1) * 64 + l) * 8);
        bb[cur ^ 1][1] = ldfrag(p1 + ((size_t)(ntb * 16 + kt + 1) * 64 + l) * 8);
      }
      __builtin_amdgcn_s_setprio(1);
#pragma unroll
      for (int m = 0; m < 4; ++m) {
        int row = m * 16 + l15;
        int byte = row * 256 + ktl * 64 + lhi * 16;
        byte ^= ((row & 15) << 4);
        bf16x8 a = *reinterpret_cast<const bf16x8*>(rbuf + byte);
        accg[m] = __builtin_amdgcn_mfma_f32_16x16x32_bf16(a, bb[cur][0], accg[m], 0, 0, 0);
        accb[m] = __builtin_amdgcn_mfma_f32_16x16x32_bf16(a, bb[cur][1], accb[m], 0, 0, 0);
      }
      __builtin_amdgcn_s_setprio(0);
    }
    if (q < 3) {
      char* wbuf = (q & 1) ? c0 : c1;   // (q+1)&1
#pragma unroll
      for (int p = 0; p < 2; ++p) {
        int g = p * 1024 + t * 2;
        int row = g >> 5, c4 = g & 31;
        int byte = row * 256 + c4 * 8;
        byte ^= ((row & 15) << 4);
        *reinterpret_cast<bf16x8*>(wbuf + byte) = pack8(cv[p * 2], cv[p * 2 + 1]);
      }
      __syncthreads();   // chunk q+1 ready; chunk q-1 reads all done
    }
  }

  // ---- FiLM -> bf16 r1 fragments into trbuf (=c0; free since end of chunk 2)
#pragma unroll
  for (int m = 0; m < 4; ++m) {
#pragma unroll
    for (int reg = 0; reg < 4; ++reg) {
      int row = m * 16 + lhi * 4 + reg;
      int colh = w * 16 + l15;
      int byte = row * 256 + colh * 2;
      byte ^= ((row & 15) << 4);
      float xv = bf2f(*reinterpret_cast<const ushort_t*>(xb + byte));
      float hv = fmaxf((accg[m][reg] + bgv) * xv + (accb[m][reg] + bbv), 0.f);
      *reinterpret_cast<ushort_t*>(c0 + byte) = f2bfh(hv);
    }
  }
  __syncthreads();   // trbuf complete

  // ---- coalesced r1 writeout ([64 rows][16 units of 16B])
#pragma unroll
  for (int it = 0; it < 2; ++it) {
    int u = it * 512 + t;
    int row = u >> 4, c16 = u & 15;
    int byte = row * 256 + c16 * 16;
    byte ^= ((row & 15) << 4);
    bf16x8 v = *reinterpret_cast<const bf16x8*>(c0 + byte);
    *reinterpret_cast<bf16x8*>(r1g + (size_t)(r0 + row) * 256 + ch * 128 + c16 * 8) = v;
  }
}

// ---------------------------------------------------------------------------
// K2: 1024 blocks x 64 rows, 8 waves; wave w owns out-cols [w*32,+32)
// (nt = w*2+tt). LDS 32KB region R: r1 bf16 [64][256] swz -> r2 in place ->
// epilogue fp32 [32][256] halves. XOR swizzle byte ^= (row&15)<<4.
// ---------------------------------------------------------------------------
__global__ __launch_bounds__(512, 2)
void k_mlp(const ushort_t* __restrict__ r1g, const float* __restrict__ x,
           const float* __restrict__ b1, const float* __restrict__ b2,
           const ushort_t* __restrict__ pW1, const ushort_t* __restrict__ pW2,
           float* __restrict__ out) {
  __shared__ __align__(16) char R[32768];
  const int r0 = blockIdx.x * 64;
  const int t = threadIdx.x;
  const int w = t >> 6;
  const int l = t & 63;
  const int l15 = l & 15;
  const int lhi = l >> 4;

  float b1v[2], b2v[2];
#pragma unroll
  for (int tt = 0; tt < 2; ++tt) {
    int col = w * 32 + tt * 16 + l15;
    b1v[tt] = b1[col];
    b2v[tt] = b2[col];
  }

  // ---- stage r1 tile (bf16, 16B/lane coalesced)
#pragma unroll
  for (int it = 0; it < 4; ++it) {
    int u = it * 512 + t;
    int row = u >> 5, c8 = u & 31;
    bf16x8 v = *reinterpret_cast<const bf16x8*>(r1g + (size_t)(r0 + row) * 256 + c8 * 8);
    int byte = row * 512 + c8 * 16;
    byte ^= ((row & 15) << 4);
    *reinterpret_cast<bf16x8*>(R + byte) = v;
  }
  bf16x8 bb2[2][2];
#pragma unroll
  for (int tt = 0; tt < 2; ++tt)
    bb2[0][tt] = ldfrag(pW1 + ((size_t)((w * 2 + tt) * 8 + 0) * 64 + l) * 8);
  __syncthreads();   // r1 staged

  // ---- GEMM2
  f32x4 acc2[4][2];
#pragma unroll
  for (int m = 0; m < 4; ++m)
#pragma unroll
    for (int n = 0; n < 2; ++n) acc2[m][n] = (f32x4){0.f, 0.f, 0.f, 0.f};

#pragma unroll
  for (int kt = 0; kt < 8; ++kt) {
    const int cur = kt & 1;
    if (kt < 7) {
#pragma unroll
      for (int tt = 0; tt < 2; ++tt)
        bb2[cur ^ 1][tt] = ldfrag(pW1 + ((size_t)((w * 2 + tt) * 8 + kt + 1) * 64 + l) * 8);
    }
    bf16x8 afr[4];
#pragma unroll
    for (int m = 0; m < 4; ++m) {
      int row = m * 16 + l15;
      int byte = row * 512 + kt * 64 + lhi * 16;
      byte ^= ((row & 15) << 4);
      afr[m] = *reinterpret_cast<const bf16x8*>(R + byte);
    }
    __builtin_amdgcn_s_setprio(1);
#pragma unroll
    for (int tt = 0; tt < 2; ++tt)
#pragma unroll
      for (int m = 0; m < 4; ++m)
        acc2[m][tt] = __builtin_amdgcn_mfma_f32_16x16x32_bf16(afr[m], bb2[cur][tt], acc2[m][tt], 0, 0, 0);
    __builtin_amdgcn_s_setprio(0);
  }
  __syncthreads();   // all r1 reads done -> in-place r2 safe

  // ---- r2 = relu(acc2+b1) in place; preload GEMM3 frags
  bf16x8 bb3[2][2];
#pragma unroll
  for (int tt = 0; tt < 2; ++tt)
    bb3[0][tt] = ldfrag(pW2 + ((size_t)((w * 2 + tt) * 8 + 0) * 64 + l) * 8);
#pragma unroll
  for (int tt = 0; tt < 2; ++tt) {
    int col = w * 32 + tt * 16 + l15;
#pragma unroll
    for (int m = 0; m < 4; ++m) {
#pragma unroll
      for (int reg = 0; reg < 4; ++reg) {
        int row = m * 16 + lhi * 4 + reg;
        int byte = row * 512 + col * 2;
        byte ^= ((row & 15) << 4);
        *reinterpret_cast<ushort_t*>(R + byte) = f2bfh(fmaxf(acc2[m][tt][reg] + b1v[tt], 0.f));
      }
    }
  }
  __syncthreads();   // r2 ready

  // ---- GEMM3
  f32x4 acc3[4][2];
#pragma unroll
  for (int m = 0; m < 4; ++m)
#pragma unroll
    for (int n = 0; n < 2; ++n) acc3[m][n] = (f32x4){0.f, 0.f, 0.f, 0.f};

#pragma unroll
  for (int kt = 0; kt < 8; ++kt) {
    const int cur = kt & 1;
    if (kt < 7) {
#pragma unroll
      for (int tt = 0; tt < 2; ++tt)
        bb3[cur ^ 1][tt] = ldfrag(pW2 + ((size_t)((w * 2 + tt) * 8 + kt + 1) * 64 + l) * 8);
    }
    bf16x8 afr[4];
#pragma unroll
    for (int m = 0; m < 4; ++m) {
      int row = m * 16 + l15;
      int byte = row * 512 + kt * 64 + lhi * 16;
      byte ^= ((row & 15) << 4);
      afr[m] = *reinterpret_cast<const bf16x8*>(R + byte);
    }
    __builtin_amdgcn_s_setprio(1);
#pragma unroll
    for (int tt = 0; tt < 2; ++tt)
#pragma unroll
      for (int m = 0; m < 4; ++m)
        acc3[m][tt] = __builtin_amdgcn_mfma_f32_16x16x32_bf16(afr[m], bb3[cur][tt], acc3[m][tt], 0, 0, 0);
    __builtin_amdgcn_s_setprio(0);
  }
  __syncthreads();   // all r2 reads done -> R free

  // ---- epilogue: two 32-row halves; +b2 at dump, +x at coalesced store
#pragma unroll
  for (int hh = 0; hh < 2; ++hh) {
    if (hh) __syncthreads();   // half-0 store reads done
#pragma unroll
    for (int tt = 0; tt < 2; ++tt) {
      int col = w * 32 + tt * 16 + l15;
#pragma unroll
      for (int mm = 0; mm < 2; ++mm) {
        int m = hh * 2 + mm;
#pragma unroll
        for (int reg = 0; reg < 4; ++reg) {
          int r = mm * 16 + lhi * 4 + reg;
          int byte = r * 1024 + col * 4;
          byte ^= ((r & 15) << 4);
          *reinterpret_cast<float*>(R + byte) = acc3[m][tt][reg] + b2v[tt];
        }
      }
    }
    __syncthreads();
#pragma unroll
    for (int i = 0; i < 4; ++i) {
      int u = i * 512 + t;
      int r = u >> 6, c4 = u & 63;   // [32 rows][64 units of 4 cols]
      int byte = r * 1024 + c4 * 16;
      byte ^= ((r & 15) << 4);
      f32x4 v = *reinterpret_cast<const f32x4*>(R + byte);
      int grow = hh * 32 + r;
      const float4 xres = *reinterpret_cast<const float4*>(
          x + (size_t)(r0 + grow) * 256 + c4 * 4);
      v.x += xres.x; v.y += xres.y; v.z += xres.z; v.w += xres.w;
      f32x4* op = reinterpret_cast<f32x4*>(out + (size_t)(r0 + grow) * 256 + c4 * 4);
      __builtin_nontemporal_store(v, op);
    }
  }
}

extern "C" void kernel_launch(void* const* d_in, const int* in_sizes, int n_in,
                              void* d_out, int out_size, void* d_ws, size_t ws_size,
                              hipStream_t stream) {
  const float* x      = (const float*)d_in[0];
  const float* cond   = (const float*)d_in[1];
  const float* W_film = (const float*)d_in[2];
  const float* b_film = (const float*)d_in[3];
  const float* W1     = (const float*)d_in[4];
  const float* b1     = (const float*)d_in[5];
  const float* W2     = (const float*)d_in[6];
  const float* b2     = (const float*)d_in[7];
  float* out = (float*)d_out;

  ushort_t* p1  = (ushort_t*)d_ws;       // 512KB
  ushort_t* pW1 = p1 + 262144;           // 128KB
  ushort_t* pW2 = pW1 + 65536;           // 128KB
  ushort_t* r1g = pW2 + 65536;           // 65536*256 bf16 = 32MB

  hipLaunchKernelGGL(pack_weights, dim3(192), dim3(256), 0, stream,
                     W_film, W1, W2, p1, pW1, pW2);
  hipLaunchKernelGGL(k_gemm1_film, dim3(2048), dim3(512), 0, stream,
                     x, cond, b_film, p1, r1g);
  hipLaunchKernelGGL(k_mlp, dim3(1024), dim3(512), 0, stream,
                     r1g, x, b1, b2, pW1, pW2, out);
}